// Round 7
// baseline (693.057 us; speedup 1.0000x reference)
//
#include <hip/hip_runtime.h>
#include <hip/hip_bf16.h>
#include <hip/hip_cooperative_groups.h>

namespace cg = cooperative_groups;

static constexpr int BB = 8;
static constexpr int DD = 32768;
static constexpr int CC = 128;
static constexpr int OO = 128;

typedef __attribute__((ext_vector_type(8))) short short8;
typedef __attribute__((ext_vector_type(4))) float f32x4;

#define LSTR 136   // padded LDS row (shorts); 136%8==0 keeps short8 16B-aligned

__device__ __forceinline__ ushort f2bf(float f) {
    __hip_bfloat16 h = __float2bfloat16(f);
    return *reinterpret_cast<ushort*>(&h);
}

// ================= Fused cooperative kernel =================
// 1024 blocks x 256 threads, 4 blocks/CU (LDS 39.4KB, VGPR<=128).
// Phase A: colsum partials (a_sh as scratch) + alpha->bf16->LDS [o][c]
// Phase B: add[b,o] = (xsum.beta + sum_c bias)/C   (8 blocks)
// Phase C: MFMA gemm, x global->reg, out = acc/C + add
__global__ __launch_bounds__(256, 4) void fused_k(
    const float* __restrict__ x, const float* __restrict__ alpha,
    const float* __restrict__ beta, const float* __restrict__ bias,
    float* __restrict__ part, float* __restrict__ add, float* __restrict__ out) {
    __shared__ __align__(16) ushort a_sh[128 * LSTR];  // 34816 B
    __shared__ float add_sh[BB * OO];                  // 4096 B
    __shared__ float xsum_sh[128];                     // 512 B
    int blk = blockIdx.x, t = threadIdx.x;

    // ---- Phase A1: column-sum partials over this block's 256 rows ----
    {
        int b = blk >> 7, chunk = blk & 127;
        long base = ((long)b * DD + (long)chunk * 256) * CC;
        int c4 = t & 31, rg = t >> 5;
        f32x4 acc = {0.f, 0.f, 0.f, 0.f};
        const float* xp = x + base + c4 * 4;
        for (int r = rg; r < 256; r += 8) {
            float4 v = *reinterpret_cast<const float4*>(xp + (long)r * CC);
            acc[0] += v.x; acc[1] += v.y; acc[2] += v.z; acc[3] += v.w;
        }
        f32x4* red = reinterpret_cast<f32x4*>(a_sh);   // scratch in a_sh
        red[t] = acc;
        __syncthreads();
        if (t < 32) {
            f32x4 s = red[t];
            #pragma unroll
            for (int g = 1; g < 8; ++g) {
                f32x4 v = red[t + g * 32];
                s[0] += v[0]; s[1] += v[1]; s[2] += v[2]; s[3] += v[3];
            }
            *reinterpret_cast<f32x4*>(part + blk * CC + t * 4) = s;
        }
        __syncthreads();
    }
    // ---- Phase A2: alpha -> bf16 transposed [o][c] into a_sh ----
    #pragma unroll
    for (int i = 0; i < 16; ++i) {
        int q = i * 256 + t;            // float4 id 0..4095
        int c = q >> 5, o4 = (q & 31) * 4;
        float4 v = *reinterpret_cast<const float4*>(alpha + c * OO + o4);
        a_sh[(o4 + 0) * LSTR + c] = f2bf(v.x);
        a_sh[(o4 + 1) * LSTR + c] = f2bf(v.y);
        a_sh[(o4 + 2) * LSTR + c] = f2bf(v.z);
        a_sh[(o4 + 3) * LSTR + c] = f2bf(v.w);
    }
    __threadfence();
    cg::this_grid().sync();

    // ---- Phase B: add vector, 8 blocks (one per batch) ----
    if (blk < BB) {
        int c = t & 127, half = t >> 7;
        float s = 0.f;
        for (int ch = half * 64; ch < half * 64 + 64; ++ch)
            s += part[(blk * 128 + ch) * CC + c];
        add_sh[half * 128 + c] = s;
        __syncthreads();
        if (t < 128) xsum_sh[t] = add_sh[t] + add_sh[128 + t];
        __syncthreads();
        float a = 0.f;
        for (int cc = half * 64; cc < half * 64 + 64; ++cc)
            a += xsum_sh[cc] * beta[cc * OO + c] + bias[cc * OO + c];
        add_sh[half * 128 + c] = a;
        __syncthreads();
        if (t < 128) add[blk * OO + t] = (add_sh[t] + add_sh[128 + t]) * (1.0f / (float)CC);
    }
    __threadfence();
    cg::this_grid().sync();

    // ---- Phase C: GEMM. Tiles aligned to phase-A rows for L2 reuse ----
    *reinterpret_cast<float4*>(&add_sh[t * 4]) = *reinterpret_cast<const float4*>(add + t * 4);
    __syncthreads();

    int w = t >> 6, l = t & 63;
    int lr = l & 15, kq = l >> 4;
    const float inv = 1.0f / (float)CC;

    for (int it = 0; it < 4; ++it) {
        int tile = blk * 16 + it * 4 + w;      // rows [blk*256, blk*256+256)
        long base = (long)tile * 16 * CC;
        int b = tile >> 11;                    // 2048 tiles per batch
        f32x4 xv[8];
        const float* xp = x + base + lr * CC + kq * 8;
        #pragma unroll
        for (int kk = 0; kk < 4; ++kk) {
            xv[kk * 2]     = *reinterpret_cast<const f32x4*>(xp + kk * 32);
            xv[kk * 2 + 1] = *reinterpret_cast<const f32x4*>(xp + kk * 32 + 4);
        }
        f32x4 acc[8];
        #pragma unroll
        for (int n = 0; n < 8; ++n) acc[n] = {0.f, 0.f, 0.f, 0.f};
        #pragma unroll
        for (int kk = 0; kk < 4; ++kk) {
            short8 af;
            #pragma unroll
            for (int j = 0; j < 4; ++j) {
                af[j]     = f2bf(xv[kk * 2][j]);
                af[4 + j] = f2bf(xv[kk * 2 + 1][j]);
            }
            #pragma unroll
            for (int n = 0; n < 8; ++n) {
                short8 bf = *reinterpret_cast<const short8*>(
                    &a_sh[(n * 16 + lr) * LSTR + kk * 32 + kq * 8]);
                acc[n] = __builtin_amdgcn_mfma_f32_16x16x32_bf16(bf, af, acc[n], 0, 0, 0);
            }
        }
        #pragma unroll
        for (int n = 0; n < 8; ++n) {
            int o0 = n * 16 + kq * 4;
            float4 ad = *reinterpret_cast<const float4*>(&add_sh[b * OO + o0]);
            float4 v;
            v.x = acc[n][0] * inv + ad.x;
            v.y = acc[n][1] * inv + ad.y;
            v.z = acc[n][2] * inv + ad.z;
            v.w = acc[n][3] * inv + ad.w;
            *reinterpret_cast<float4*>(out + base + (long)lr * OO + o0) = v;
        }
    }
}

// ================= Fallback path (proven R3 kernels) =================
__global__ __launch_bounds__(256) void colsum_k(const float* __restrict__ x,
                                                const float* __restrict__ alpha,
                                                float* __restrict__ part,
                                                ushort* __restrict__ alphaT) {
    int blk = blockIdx.x;
    int t = threadIdx.x;
    if (blk >= 1024) {
        int e = (blk - 1024) * 1024 + t * 4;
        #pragma unroll
        for (int j = 0; j < 4; ++j) {
            int g = e + j;
            int o = g >> 7, c = g & 127;
            alphaT[g] = f2bf(alpha[c * OO + o]);
        }
        return;
    }
    int b = blk >> 7, chunk = blk & 127;
    long base = ((long)b * DD + (long)chunk * 256) * CC;
    int c4 = t & 31, rg = t >> 5;
    f32x4 acc = {0.f, 0.f, 0.f, 0.f};
    const float* xp = x + base + c4 * 4;
    for (int r = rg; r < 256; r += 8) {
        float4 v = *reinterpret_cast<const float4*>(xp + (long)r * CC);
        acc[0] += v.x; acc[1] += v.y; acc[2] += v.z; acc[3] += v.w;
    }
    __shared__ f32x4 red[256];
    red[t] = acc;
    __syncthreads();
    if (t < 32) {
        f32x4 s = red[t];
        #pragma unroll
        for (int g = 1; g < 8; ++g) {
            f32x4 v = red[t + g * 32];
            s[0] += v[0]; s[1] += v[1]; s[2] += v[2]; s[3] += v[3];
        }
        *reinterpret_cast<f32x4*>(part + blk * CC + t * 4) = s;
    }
}

__global__ __launch_bounds__(256) void addvec_k(const float* __restrict__ part,
                                                const float* __restrict__ beta,
                                                const float* __restrict__ bias,
                                                float* __restrict__ add) {
    int b = blockIdx.x;
    int t = threadIdx.x;
    int c = t & 127, half = t >> 7;
    __shared__ float xs2[2][128];
    __shared__ float xsum[128];
    float s = 0.f;
    for (int ch = half * 64; ch < half * 64 + 64; ++ch)
        s += part[(b * 128 + ch) * CC + c];
    xs2[half][c] = s;
    __syncthreads();
    if (t < 128) xsum[t] = xs2[0][t] + xs2[1][t];
    __syncthreads();
    float a = 0.f;
    for (int cc = half * 64; cc < half * 64 + 64; ++cc)
        a += xsum[cc] * beta[cc * OO + c] + bias[cc * OO + c];
    xs2[half][c] = a;
    __syncthreads();
    if (t < 128) add[b * OO + t] = (xs2[0][t] + xs2[1][t]) * (1.0f / (float)CC);
}

__global__ __launch_bounds__(256) void gemm_k(const float* __restrict__ x,
                                              const ushort* __restrict__ alphaT,
                                              const float* __restrict__ add,
                                              float* __restrict__ out) {
    __shared__ __align__(16) ushort a_sh[128 * LSTR];
    __shared__ float add_sh[BB * OO];
    int t = threadIdx.x;
    #pragma unroll
    for (int i = 0; i < 8; ++i) {
        int ci = i * 256 + t;
        int o = ci >> 4, cseg = (ci & 15) * 8;
        short8 v = *reinterpret_cast<const short8*>(alphaT + o * CC + cseg);
        *reinterpret_cast<short8*>(&a_sh[o * LSTR + cseg]) = v;
    }
    *reinterpret_cast<float4*>(&add_sh[t * 4]) = *reinterpret_cast<const float4*>(add + t * 4);
    __syncthreads();

    int w = t >> 6, l = t & 63;
    int lr = l & 15, kq = l >> 4;
    int wid = blockIdx.x * 4 + w;
    const float inv = 1.0f / (float)CC;

    for (int it = 0; it < 4; ++it) {
        int tile = wid + it * 4096;
        long base = (long)tile * 16 * CC;
        int b = tile >> 11;
        f32x4 xv[8];
        const float* xp = x + base + lr * CC + kq * 8;
        #pragma unroll
        for (int kk = 0; kk < 4; ++kk) {
            xv[kk * 2]     = *reinterpret_cast<const f32x4*>(xp + kk * 32);
            xv[kk * 2 + 1] = *reinterpret_cast<const f32x4*>(xp + kk * 32 + 4);
        }
        f32x4 acc[8];
        #pragma unroll
        for (int n = 0; n < 8; ++n) acc[n] = {0.f, 0.f, 0.f, 0.f};
        #pragma unroll
        for (int kk = 0; kk < 4; ++kk) {
            short8 af;
            #pragma unroll
            for (int j = 0; j < 4; ++j) {
                af[j]     = f2bf(xv[kk * 2][j]);
                af[4 + j] = f2bf(xv[kk * 2 + 1][j]);
            }
            #pragma unroll
            for (int n = 0; n < 8; ++n) {
                short8 bf = *reinterpret_cast<const short8*>(
                    &a_sh[(n * 16 + lr) * LSTR + kk * 32 + kq * 8]);
                acc[n] = __builtin_amdgcn_mfma_f32_16x16x32_bf16(bf, af, acc[n], 0, 0, 0);
            }
        }
        #pragma unroll
        for (int n = 0; n < 8; ++n) {
            int o0 = n * 16 + kq * 4;
            float4 ad = *reinterpret_cast<const float4*>(&add_sh[b * OO + o0]);
            float4 v;
            v.x = acc[n][0] * inv + ad.x;
            v.y = acc[n][1] * inv + ad.y;
            v.z = acc[n][2] * inv + ad.z;
            v.w = acc[n][3] * inv + ad.w;
            *reinterpret_cast<float4*>(out + base + (long)lr * OO + o0) = v;
        }
    }
}

extern "C" void kernel_launch(void* const* d_in, const int* in_sizes, int n_in,
                              void* d_out, int out_size, void* d_ws, size_t ws_size,
                              hipStream_t stream) {
    const float* x     = (const float*)d_in[0];
    const float* alpha = (const float*)d_in[1];
    const float* beta  = (const float*)d_in[2];
    const float* bias  = (const float*)d_in[3];
    float* out = (float*)d_out;

    // ws: part [0,512K) ; add [512K,516K) ; alphaT [516K,548K) (fallback only)
    float*  part   = (float*)d_ws;
    float*  add    = (float*)((char*)d_ws + 524288);
    ushort* alphaT = (ushort*)((char*)d_ws + 528384);

    void* args[] = {(void*)&x, (void*)&alpha, (void*)&beta, (void*)&bias,
                    (void*)&part, (void*)&add, (void*)&out};
    hipError_t e = hipLaunchCooperativeKernel((const void*)fused_k, dim3(1024), dim3(256),
                                              args, 0, stream);
    if (e != hipSuccess) {
        // deterministic fallback: proven 3-kernel path
        colsum_k<<<1040, 256, 0, stream>>>(x, alpha, part, alphaT);
        addvec_k<<<8,    256, 0, stream>>>(part, beta, bias, add);
        gemm_k<<<1024,   256, 0, stream>>>(x, alphaT, add, out);
    }
}

// Round 10
// 266.206 us; speedup vs baseline: 2.6035x; 2.6035x over previous
//
#include <hip/hip_runtime.h>
#include <hip/hip_bf16.h>

static constexpr int BB = 8;
static constexpr int DD = 32768;
static constexpr int CC = 128;
static constexpr int OO = 128;

typedef __attribute__((ext_vector_type(8))) short short8;
typedef __attribute__((ext_vector_type(4))) float f32x4;

__device__ __forceinline__ ushort f2bf(float f) {
    __hip_bfloat16 h = __float2bfloat16(f);
    return *reinterpret_cast<ushort*>(&h);
}

// ---------------- Kernel 1: colsum partials + alpha fragment-pack tail ----------
// blocks 0..1023: part[blk][c] = sum of 256 rows of x   (blk = b*128 + chunk)
// blocks 1024..1031: alphaF fragment-ordered bf16 pack (2048 short8 fragments):
//   fragment (kk,n), lane l (lr=l&15,kq=l>>4), elem j = alpha[kk*32+kq*8+j][n*16+lr]
__global__ __launch_bounds__(256) void colsum_k(const float* __restrict__ x,
                                                const float* __restrict__ alpha,
                                                float* __restrict__ part,
                                                ushort* __restrict__ alphaF) {
    int blk = blockIdx.x;
    int t = threadIdx.x;
    if (blk >= 1024) {
        int fid = (blk - 1024) * 256 + t;      // 0..2047
        int kk = fid >> 9, n = (fid >> 6) & 7, l = fid & 63;
        int lr = l & 15, kq = l >> 4;
        int o = n * 16 + lr;
        int c0 = kk * 32 + kq * 8;
        short8 fr;
        #pragma unroll
        for (int j = 0; j < 8; ++j)
            fr[j] = f2bf(alpha[(c0 + j) * OO + o]);
        *reinterpret_cast<short8*>(alphaF + fid * 8) = fr;
        return;
    }
    int b = blk >> 7, chunk = blk & 127;
    long base = ((long)b * DD + (long)chunk * 256) * CC;
    int c4 = t & 31, rg = t >> 5;
    f32x4 acc = {0.f, 0.f, 0.f, 0.f};
    const float* xp = x + base + c4 * 4;
    for (int r = rg; r < 256; r += 8) {
        float4 v = *reinterpret_cast<const float4*>(xp + (long)r * CC);
        acc[0] += v.x; acc[1] += v.y; acc[2] += v.z; acc[3] += v.w;
    }
    __shared__ f32x4 red[256];
    red[t] = acc;
    __syncthreads();
    if (t < 32) {
        f32x4 s = red[t];
        #pragma unroll
        for (int g = 1; g < 8; ++g) {
            f32x4 v = red[t + g * 32];
            s[0] += v[0]; s[1] += v[1]; s[2] += v[2]; s[3] += v[3];
        }
        *reinterpret_cast<f32x4*>(part + blk * CC + t * 4) = s;
    }
}

// ---------------- Kernel 2: reduce partials -> xsum -> add[b,o] -------------------
__global__ __launch_bounds__(256) void addvec_k(const float* __restrict__ part,
                                                const float* __restrict__ beta,
                                                const float* __restrict__ bias,
                                                float* __restrict__ add) {
    int b = blockIdx.x;
    int t = threadIdx.x;
    int c = t & 127, half = t >> 7;
    __shared__ float xs2[2][128];
    __shared__ float xsum[128];
    float s = 0.f;
    for (int ch = half * 64; ch < half * 64 + 64; ++ch)
        s += part[(b * 128 + ch) * CC + c];
    xs2[half][c] = s;
    __syncthreads();
    if (t < 128) xsum[t] = xs2[0][t] + xs2[1][t];
    __syncthreads();
    float a = 0.f;
    for (int cc = half * 64; cc < half * 64 + 64; ++cc)
        a += xsum[cc] * beta[cc * OO + c] + bias[cc * OO + c];
    xs2[half][c] = a;
    __syncthreads();
    if (t < 128) add[b * OO + t] = (xs2[0][t] + xs2[1][t]) * (1.0f / (float)CC);
}

// ---------------- Kernel 3: MFMA GEMM, fragment-ordered alpha in LDS --------------
// 1024 blocks x 4 waves; each wave: 16-row tile, 4 tiles grid-strided.
// a_sh linear fragment order: lane l reads a_sh[((kk*8+n)*64+l)*8] -> 64 consecutive
// 16B slots per wave-read -> conflict-free ds_read_b128 (LDS minimum cycles).
__global__ __launch_bounds__(256) void gemm_k(const float* __restrict__ x,
                                              const ushort* __restrict__ alphaF,
                                              const float* __restrict__ add,
                                              float* __restrict__ out) {
    __shared__ __align__(16) ushort a_sh[16384];   // 32 KiB, fragment-ordered
    __shared__ float add_sh[BB * OO];              // 4 KiB
    int t = threadIdx.x;
    #pragma unroll
    for (int i = 0; i < 8; ++i) {
        int e = (i * 256 + t) * 8;
        *reinterpret_cast<short8*>(&a_sh[e]) =
            *reinterpret_cast<const short8*>(alphaF + e);
    }
    *reinterpret_cast<float4*>(&add_sh[t * 4]) = *reinterpret_cast<const float4*>(add + t * 4);
    __syncthreads();

    int w = t >> 6, l = t & 63;
    int lr = l & 15, kq = l >> 4;
    int wid = blockIdx.x * 4 + w;          // 0..4095
    const float inv = 1.0f / (float)CC;

    for (int it = 0; it < 4; ++it) {
        int tile = wid + it * 4096;        // 0..16383 (16 rows each)
        long base = (long)tile * 16 * CC;
        int b = tile >> 11;                // 2048 tiles per batch
        f32x4 xv[8];
        const float* xp = x + base + lr * CC + kq * 8;
        #pragma unroll
        for (int kk = 0; kk < 4; ++kk) {
            xv[kk * 2]     = *reinterpret_cast<const f32x4*>(xp + kk * 32);
            xv[kk * 2 + 1] = *reinterpret_cast<const f32x4*>(xp + kk * 32 + 4);
        }
        f32x4 acc[8];
        #pragma unroll
        for (int n = 0; n < 8; ++n) acc[n] = {0.f, 0.f, 0.f, 0.f};
        #pragma unroll
        for (int kk = 0; kk < 4; ++kk) {
            short8 af;
            #pragma unroll
            for (int j = 0; j < 4; ++j) {
                af[j]     = f2bf(xv[kk * 2][j]);
                af[4 + j] = f2bf(xv[kk * 2 + 1][j]);
            }
            #pragma unroll
            for (int n = 0; n < 8; ++n) {
                short8 bf = *reinterpret_cast<const short8*>(
                    &a_sh[((kk * 8 + n) * 64 + l) * 8]);
                acc[n] = __builtin_amdgcn_mfma_f32_16x16x32_bf16(bf, af, acc[n], 0, 0, 0);
            }
        }
        #pragma unroll
        for (int n = 0; n < 8; ++n) {
            int o0 = n * 16 + kq * 4;      // D: col=lane&15 (=x row), row=(lane>>4)*4+j (=o)
            float4 ad = *reinterpret_cast<const float4*>(&add_sh[b * OO + o0]);
            float4 v;
            v.x = acc[n][0] * inv + ad.x;
            v.y = acc[n][1] * inv + ad.y;
            v.z = acc[n][2] * inv + ad.z;
            v.w = acc[n][3] * inv + ad.w;
            *reinterpret_cast<float4*>(out + base + (long)lr * OO + o0) = v;
        }
    }
}

extern "C" void kernel_launch(void* const* d_in, const int* in_sizes, int n_in,
                              void* d_out, int out_size, void* d_ws, size_t ws_size,
                              hipStream_t stream) {
    const float* x     = (const float*)d_in[0];
    const float* alpha = (const float*)d_in[1];
    const float* beta  = (const float*)d_in[2];
    const float* bias  = (const float*)d_in[3];
    float* out = (float*)d_out;

    // ws: part [0,512K) ; add [512K,516K) ; alphaF [516K,548K)
    float*  part   = (float*)d_ws;
    float*  add    = (float*)((char*)d_ws + 524288);
    ushort* alphaF = (ushort*)((char*)d_ws + 528384);

    colsum_k<<<1032, 256, 0, stream>>>(x, alpha, part, alphaF);
    addvec_k<<<8,    256, 0, stream>>>(part, beta, bias, add);
    gemm_k<<<1024,   256, 0, stream>>>(x, alphaF, add, out);
}